// Round 1
// baseline (1214.545 us; speedup 1.0000x reference)
//
#include <hip/hip_runtime.h>
#include <hip/hip_bf16.h>
#include <stdint.h>

#define N_NODES 50000
#define N_EDGES 800000
#define H 128

typedef short bf16x8 __attribute__((ext_vector_type(8)));
typedef float f32x4 __attribute__((ext_vector_type(4)));

__device__ __forceinline__ short f2bfs(float f) {
    __hip_bfloat16 h = __float2bfloat16(f);   // HW RNE cvt on gfx950
    return *(short*)&h;
}

__device__ __forceinline__ bf16x8 cvt8(const float* __restrict__ p) {
    const float4* q = (const float4*)p;
    float4 a = q[0], b = q[1];
    bf16x8 r;
    r[0] = f2bfs(a.x); r[1] = f2bfs(a.y); r[2] = f2bfs(a.z); r[3] = f2bfs(a.w);
    r[4] = f2bfs(b.x); r[5] = f2bfs(b.y); r[6] = f2bfs(b.z); r[7] = f2bfs(b.w);
    return r;
}

// ---- weight repack: fp32 [K x 128] -> bf16 fragment-linear [kt][nt][lane][8]
// element (kt,nt,lane,j) = W[(kt*32 + (lane>>4)*8 + j) * 128 + nt*16 + (lane&15)]
// buffers (bf16 elem offsets in ws):
//   BW1 @ 0      (We1, K=384, 96 frags)   BW2 @ 49152 (We2, K=128)
//   BN1 @ 65536  (Wn1, K=256)             BN2 @ 98304 (Wn2, K=128)   total 114688
__global__ void prep_weights(const float* __restrict__ We1, const float* __restrict__ We2,
                             const float* __restrict__ Wn1, const float* __restrict__ Wn2,
                             unsigned short* __restrict__ wb) {
    int i = blockIdx.x * 256 + threadIdx.x;
    if (i >= 114688) return;
    const float* W; int idx;
    if (i < 49152)      { W = We1; idx = i; }
    else if (i < 65536) { W = We2; idx = i - 49152; }
    else if (i < 98304) { W = Wn1; idx = i - 65536; }
    else                { W = Wn2; idx = i - 98304; }
    int f = idx >> 9, lane = (idx >> 3) & 63, j = idx & 7;
    int kt = f >> 3, nt = f & 7;
    int k = kt * 32 + (lane >> 4) * 8 + j;
    int n = nt * 16 + (lane & 15);
    wb[i] = (unsigned short)f2bfs(W[k * H + n]);
}

// ---- x fp32 -> bf16 (one-time; same RNE rounding the MFMA path applied anyway)
__global__ void prep_x(const float* __restrict__ x, unsigned short* __restrict__ xb) {
    int i = blockIdx.x * 256 + threadIdx.x;       // one 8-elem chunk per thread
    if (i >= (N_NODES * H) / 8) return;
    bf16x8 v = cvt8(x + (size_t)i * 8);
    *(bf16x8*)(xb + (size_t)i * 8) = v;
}

// ---- counting sort of edges by destination (col) ----
__global__ void hist_col(const int* __restrict__ ei, int* __restrict__ cnt) {
    int e = blockIdx.x * 256 + threadIdx.x;
    if (e < N_EDGES) atomicAdd(&cnt[ei[N_EDGES + e]], 1);
}

// exclusive scan of cnt[50000] -> cursor[50000], single block of 1024
__global__ void scan_hist(const int* __restrict__ cnt, int* __restrict__ cursor) {
    __shared__ int wsum[16];
    __shared__ int stot;
    __shared__ int sbase_s;
    const int tid = threadIdx.x;
    const int lane = tid & 63, wid = tid >> 6;
    if (tid == 0) sbase_s = 0;
    __syncthreads();
    for (int base = 0; base < N_NODES; base += 1024) {
        int i = base + tid;
        int v = (i < N_NODES) ? cnt[i] : 0;
        int incl = v;
#pragma unroll
        for (int off = 1; off < 64; off <<= 1) {
            int t = __shfl_up(incl, off);
            if (lane >= off) incl += t;
        }
        if (lane == 63) wsum[wid] = incl;
        __syncthreads();
        if (wid == 0) {
            int wv = (lane < 16) ? wsum[lane] : 0;
            int winc = wv;
#pragma unroll
            for (int off = 1; off < 16; off <<= 1) {
                int t = __shfl_up(winc, off);
                if (lane >= off) winc += t;
            }
            if (lane < 16) wsum[lane] = winc - wv;   // exclusive wave base
            if (lane == 15) stot = winc;             // tile total
        }
        __syncthreads();
        if (i < N_NODES) cursor[i] = sbase_s + wsum[wid] + (incl - v);
        __syncthreads();
        if (tid == 0) sbase_s += stot;
        __syncthreads();
    }
}

__global__ void build_perm(const int* __restrict__ ei, int* __restrict__ cursor,
                           int* __restrict__ perm) {
    int e = blockIdx.x * 256 + threadIdx.x;
    if (e < N_EDGES) {
        int pos = atomicAdd(&cursor[ei[N_EDGES + e]], 1);
        perm[pos] = e;
    }
}

// ---- edge MLP + segmented scatter-add. 1 wave = 32 dest-sorted edges, block = 4 waves.
__launch_bounds__(256)
__global__ void edge_mlp(const unsigned short* __restrict__ xb,
                         const int* __restrict__ ei,
                         const float* __restrict__ ea,
                         const float* __restrict__ be1,
                         const float* __restrict__ be2,
                         const unsigned short* __restrict__ wb,
                         const int* __restrict__ perm,
                         float* __restrict__ agg) {
    // per-wave 8 KiB, dual-purpose: bf16 h staging [2][4][64][8], then fp32 msg tile [16][128]
    __shared__ __align__(16) char smem[4][8192];   // 32 KiB
    const int tid = threadIdx.x;
    const int wave = tid >> 6, lane = tid & 63;
    const int c = lane & 15, quad = lane >> 4;
    const int e0 = (blockIdx.x * 4 + wave) * 32;

    short (*hb)[4][64][8] = (short (*)[4][64][8])smem[wave];
    float* msg = (float*)smem[wave];

    const bf16x8* __restrict__ BW1 = (const bf16x8*)wb;
    const bf16x8* __restrict__ BW2 = (const bf16x8*)(wb + 49152);

    float be1v[8], be2v[8];
#pragma unroll
    for (int nt = 0; nt < 8; ++nt) {
        be1v[nt] = be1[nt * 16 + c];
        be2v[nt] = be2[nt * 16 + c];
    }

    // sorted position -> original edge, and its destination (non-decreasing in position)
    int myp = 0, myd = 0;
    if (lane < 32) { myp = perm[e0 + lane]; myd = ei[N_EDGES + myp]; }

    const unsigned short* pxb[2][2];
    const float* pea[2];
#pragma unroll
    for (int t = 0; t < 2; ++t) {
        int p_tc = __shfl(myp, t * 16 + c);
        int d_tc = __shfl(myd, t * 16 + c);
        int r_tc = ei[p_tc];
        pxb[t][0] = xb + (size_t)r_tc * H;
        pxb[t][1] = xb + (size_t)d_tc * H;
        pea[t]    = ea + (size_t)p_tc * H;
    }

    f32x4 acc[2][8];
#pragma unroll
    for (int t = 0; t < 2; ++t)
#pragma unroll
        for (int nt = 0; nt < 8; ++nt)
            acc[t][nt] = (f32x4){be1v[nt], be1v[nt], be1v[nt], be1v[nt]};

#pragma unroll
    for (int kt = 0; kt < 12; ++kt) {
        const int off = (kt & 3) * 32 + quad * 8;
        bf16x8 a0, a1;
        if (kt < 8) {          // x[row], x[col] — pre-converted bf16, direct 16B load
            a0 = *(const bf16x8*)(pxb[0][kt >> 2] + off);
            a1 = *(const bf16x8*)(pxb[1][kt >> 2] + off);
        } else {               // edge_attr — fp32, cvt inline
            a0 = cvt8(pea[0] + off);
            a1 = cvt8(pea[1] + off);
        }
#pragma unroll
        for (int nt = 0; nt < 8; ++nt) {
            bf16x8 b = BW1[(kt * 8 + nt) * 64 + lane];
            acc[0][nt] = __builtin_amdgcn_mfma_f32_16x16x32_bf16(a0, b, acc[0][nt], 0, 0, 0);
            acc[1][nt] = __builtin_amdgcn_mfma_f32_16x16x32_bf16(a1, b, acc[1][nt], 0, 0, 0);
        }
    }

    // relu + store h to LDS in GEMM2 A-fragment order
#pragma unroll
    for (int t = 0; t < 2; ++t)
#pragma unroll
        for (int nt = 0; nt < 8; ++nt) {
            int kt2 = nt >> 1;
            int laneq = 16 * ((nt * 2 + (c >> 3)) & 3);
#pragma unroll
            for (int r = 0; r < 4; ++r) {
                float v = acc[t][nt][r];
                v = v > 0.f ? v : 0.f;
                hb[t][kt2][quad * 4 + r + laneq][c & 7] = f2bfs(v);
            }
        }
    __syncthreads();

    f32x4 acc2[2][8];
#pragma unroll
    for (int t = 0; t < 2; ++t)
#pragma unroll
        for (int nt = 0; nt < 8; ++nt)
            acc2[t][nt] = (f32x4){be2v[nt], be2v[nt], be2v[nt], be2v[nt]};

#pragma unroll
    for (int kt = 0; kt < 4; ++kt) {
        bf16x8 a0 = *(const bf16x8*)&hb[0][kt][lane][0];
        bf16x8 a1 = *(const bf16x8*)&hb[1][kt][lane][0];
#pragma unroll
        for (int nt = 0; nt < 8; ++nt) {
            bf16x8 b = BW2[(kt * 8 + nt) * 64 + lane];
            acc2[0][nt] = __builtin_amdgcn_mfma_f32_16x16x32_bf16(a0, b, acc2[0][nt], 0, 0, 0);
            acc2[1][nt] = __builtin_amdgcn_mfma_f32_16x16x32_bf16(a1, b, acc2[1][nt], 0, 0, 0);
        }
    }
    __syncthreads();   // all hb (bf16) reads done before fp32 msg overwrite

    // segmented scatter: stage 16x128 msg tile (XOR-swizzled, conflict-free),
    // then wave-uniform run detection over sorted dests -> one coalesced
    // 2x128-float atomic flush per run (avg ~2 runs/tile vs 64 atomics/tile before)
#pragma unroll
    for (int t = 0; t < 2; ++t) {
#pragma unroll
        for (int nt = 0; nt < 8; ++nt)
#pragma unroll
            for (int r = 0; r < 4; ++r)
                msg[(quad * 4 + r) * 128 + ((nt * 16 + c) ^ (quad * 8))] = acc2[t][nt][r];
        __syncthreads();

        float s0 = 0.f, s1 = 0.f;
        int dprev = __builtin_amdgcn_readlane(myd, t * 16);
#pragma unroll
        for (int i = 0; i < 16; ++i) {
            int di = __builtin_amdgcn_readlane(myd, t * 16 + i);   // uniform (SGPR)
            int idx = i * 128 + (lane ^ ((i >> 2) * 8));
            float v0 = msg[idx];
            float v1 = msg[idx + 64];
            if (i > 0 && di != dprev) {
                atomicAdd(agg + (size_t)dprev * H + lane, s0);
                atomicAdd(agg + (size_t)dprev * H + 64 + lane, s1);
                s0 = v0; s1 = v1; dprev = di;
            } else {
                s0 += v0; s1 += v1;
            }
        }
        atomicAdd(agg + (size_t)dprev * H + lane, s0);
        atomicAdd(agg + (size_t)dprev * H + 64 + lane, s1);
        __syncthreads();   // WAR guard before next tile restages same LDS
    }
}

// ---- node MLP: inputs concat(x[v], agg[v]) [N x 256] -> 128 -> 128
// 2 waves/block (128 thr) -> 782 blocks: fixes the 391-block grid quantization
__launch_bounds__(128)
__global__ void node_mlp(const unsigned short* __restrict__ xb,
                         const float* __restrict__ agg,
                         const float* __restrict__ bn1,
                         const float* __restrict__ bn2,
                         const unsigned short* __restrict__ wb,
                         float* __restrict__ out) {
    __shared__ __align__(16) char smem[2][8192];
    const int tid = threadIdx.x;
    const int wave = tid >> 6, lane = tid & 63;
    const int c = lane & 15, quad = lane >> 4;
    const int v0 = (blockIdx.x * 2 + wave) * 32;
    short (*hb)[4][64][8] = (short (*)[4][64][8])smem[wave];

    const bf16x8* __restrict__ BN1 = (const bf16x8*)(wb + 65536);
    const bf16x8* __restrict__ BN2 = (const bf16x8*)(wb + 98304);

    float b1v[8], b2v[8];
#pragma unroll
    for (int nt = 0; nt < 8; ++nt) {
        b1v[nt] = bn1[nt * 16 + c];
        b2v[nt] = bn2[nt * 16 + c];
    }

    const unsigned short* pxb[2];
    const float* pag[2];
#pragma unroll
    for (int t = 0; t < 2; ++t) {
        int v = v0 + t * 16 + c;
        v = v < N_NODES ? v : N_NODES - 1;   // clamp; garbage rows never stored
        pxb[t] = xb  + (size_t)v * H;
        pag[t] = agg + (size_t)v * H;
    }

    f32x4 acc[2][8];
#pragma unroll
    for (int t = 0; t < 2; ++t)
#pragma unroll
        for (int nt = 0; nt < 8; ++nt)
            acc[t][nt] = (f32x4){b1v[nt], b1v[nt], b1v[nt], b1v[nt]};

#pragma unroll
    for (int kt = 0; kt < 8; ++kt) {
        const int off = (kt & 3) * 32 + quad * 8;
        bf16x8 a0, a1;
        if (kt < 4) {
            a0 = *(const bf16x8*)(pxb[0] + off);
            a1 = *(const bf16x8*)(pxb[1] + off);
        } else {
            a0 = cvt8(pag[0] + off);
            a1 = cvt8(pag[1] + off);
        }
#pragma unroll
        for (int nt = 0; nt < 8; ++nt) {
            bf16x8 b = BN1[(kt * 8 + nt) * 64 + lane];
            acc[0][nt] = __builtin_amdgcn_mfma_f32_16x16x32_bf16(a0, b, acc[0][nt], 0, 0, 0);
            acc[1][nt] = __builtin_amdgcn_mfma_f32_16x16x32_bf16(a1, b, acc[1][nt], 0, 0, 0);
        }
    }

#pragma unroll
    for (int t = 0; t < 2; ++t)
#pragma unroll
        for (int nt = 0; nt < 8; ++nt) {
            int kt2 = nt >> 1;
            int laneq = 16 * ((nt * 2 + (c >> 3)) & 3);
#pragma unroll
            for (int r = 0; r < 4; ++r) {
                float v = acc[t][nt][r];
                v = v > 0.f ? v : 0.f;
                hb[t][kt2][quad * 4 + r + laneq][c & 7] = f2bfs(v);
            }
        }
    __syncthreads();

    f32x4 acc2[2][8];
#pragma unroll
    for (int t = 0; t < 2; ++t)
#pragma unroll
        for (int nt = 0; nt < 8; ++nt)
            acc2[t][nt] = (f32x4){b2v[nt], b2v[nt], b2v[nt], b2v[nt]};

#pragma unroll
    for (int kt = 0; kt < 4; ++kt) {
        bf16x8 a0 = *(const bf16x8*)&hb[0][kt][lane][0];
        bf16x8 a1 = *(const bf16x8*)&hb[1][kt][lane][0];
#pragma unroll
        for (int nt = 0; nt < 8; ++nt) {
            bf16x8 b = BN2[(kt * 8 + nt) * 64 + lane];
            acc2[0][nt] = __builtin_amdgcn_mfma_f32_16x16x32_bf16(a0, b, acc2[0][nt], 0, 0, 0);
            acc2[1][nt] = __builtin_amdgcn_mfma_f32_16x16x32_bf16(a1, b, acc2[1][nt], 0, 0, 0);
        }
    }

#pragma unroll
    for (int t = 0; t < 2; ++t)
#pragma unroll
        for (int nt = 0; nt < 8; ++nt)
#pragma unroll
            for (int r = 0; r < 4; ++r) {
                int v = v0 + t * 16 + quad * 4 + r;
                if (v < N_NODES)
                    out[(size_t)v * H + nt * 16 + c] = acc2[t][nt][r];
            }
}

extern "C" void kernel_launch(void* const* d_in, const int* in_sizes, int n_in,
                              void* d_out, int out_size, void* d_ws, size_t ws_size,
                              hipStream_t stream) {
    const float* x   = (const float*)d_in[0];
    const int*   ei  = (const int*)d_in[1];
    const float* ea  = (const float*)d_in[2];
    const float* We1 = (const float*)d_in[3];
    const float* be1 = (const float*)d_in[4];
    const float* We2 = (const float*)d_in[5];
    const float* be2 = (const float*)d_in[6];
    const float* Wn1 = (const float*)d_in[7];
    const float* bn1 = (const float*)d_in[8];
    const float* Wn2 = (const float*)d_in[9];
    const float* bn2 = (const float*)d_in[10];
    float* out = (float*)d_out;

    // workspace layout (42.3 MB total):
    //   [0, 256K)        weight frags (bf16)
    //   [256K, +25.6M)   agg fp32 accumulator
    //   [+25.6M, +200K)  cnt   (degree histogram)
    //   [+..,   +200K)   cursor (scan result, consumed by build_perm)
    //   [+..,   +3.2M)   perm  (edges sorted by destination)
    //   [+..,  +12.8M)   x in bf16
    char* base = (char*)d_ws;
    unsigned short* wb   = (unsigned short*)base;
    float*          agg  = (float*)(base + 262144);
    int*            cnt  = (int*)(base + 25862144);
    int*            cur  = (int*)(base + 26066944);
    int*            perm = (int*)(base + 26271744);
    unsigned short* xbuf = (unsigned short*)(base + 29471744);

    // zero agg + cnt in one contiguous memset
    hipMemsetAsync(agg, 0, 25600000 + 204800, stream);
    prep_weights<<<448, 256, 0, stream>>>(We1, We2, Wn1, Wn2, wb);
    prep_x<<<3125, 256, 0, stream>>>(x, xbuf);
    hist_col<<<3125, 256, 0, stream>>>(ei, cnt);
    scan_hist<<<1, 1024, 0, stream>>>(cnt, cur);
    build_perm<<<3125, 256, 0, stream>>>(ei, cur, perm);
    edge_mlp<<<6250, 256, 0, stream>>>(xbuf, ei, ea, be1, be2, wb, perm, agg);
    node_mlp<<<782, 128, 0, stream>>>(xbuf, agg, bn1, bn2, wb, out);
}

// Round 2
// 1027.364 us; speedup vs baseline: 1.1822x; 1.1822x over previous
//
#include <hip/hip_runtime.h>
#include <hip/hip_bf16.h>
#include <stdint.h>

#define N_NODES 50000
#define N_EDGES 800000
#define H 128
#define CHUNK 100000   // edges per EW chunk (8 chunks, 25.6MB bf16 each)

typedef short bf16x8 __attribute__((ext_vector_type(8)));
typedef float f32x4 __attribute__((ext_vector_type(4)));

__device__ __forceinline__ short f2bfs(float f) {
    __hip_bfloat16 h = __float2bfloat16(f);   // HW RNE cvt on gfx950
    return *(short*)&h;
}
__device__ __forceinline__ float bfs2f(unsigned short u) {
    return __uint_as_float(((unsigned int)u) << 16);   // exact
}

__device__ __forceinline__ bf16x8 cvt8(const float* __restrict__ p) {
    const float4* q = (const float4*)p;
    float4 a = q[0], b = q[1];
    bf16x8 r;
    r[0] = f2bfs(a.x); r[1] = f2bfs(a.y); r[2] = f2bfs(a.z); r[3] = f2bfs(a.w);
    r[4] = f2bfs(b.x); r[5] = f2bfs(b.y); r[6] = f2bfs(b.z); r[7] = f2bfs(b.w);
    return r;
}

// ---- Wfuse = We2 @ Wn1[128:256]  (fp32, exact path for the folded GEMM2)
//      c2[n] = sum_m be2[m] * Wn1[128+m][n]
__global__ void wfuse_c2(const float* __restrict__ We2, const float* __restrict__ Wn1,
                         const float* __restrict__ be2,
                         float* __restrict__ wfuse, float* __restrict__ c2) {
    int k = blockIdx.x;       // 0..127 -> wfuse row; 128 -> c2
    int n = threadIdx.x;      // 128 threads
    float s = 0.f;
    if (k < 128) {
        for (int m = 0; m < 128; ++m) s += We2[k * 128 + m] * Wn1[(128 + m) * 128 + n];
        wfuse[k * 128 + n] = s;
    } else {
        for (int m = 0; m < 128; ++m) s += be2[m] * Wn1[(128 + m) * 128 + n];
        c2[n] = s;
    }
}

// ---- weight repack: fp32 [K x 128] -> bf16 fragment-linear [kt][nt][lane][8]
// element (kt,nt,lane,j) = W[(kt*32 + (lane>>4)*8 + j) * 128 + nt*16 + (lane&15)]
// wb layout (ush elems): BW1 @0 (We1, 96 frags), BN1 @49152 ([Wn1a;Wfuse], 64), BN2 @81920 (Wn2, 32)
__global__ void prep_weights(const float* __restrict__ We1, const float* __restrict__ Wn1,
                             const float* __restrict__ Wn2, const float* __restrict__ wfuse,
                             unsigned short* __restrict__ wb) {
    int i = blockIdx.x * 256 + threadIdx.x;
    if (i >= 98304) return;
    const float* W; int idx; int which;
    if (i < 49152)      { W = We1; idx = i; which = 0; }
    else if (i < 81920) { W = Wn1; idx = i - 49152; which = 1; }
    else                { W = Wn2; idx = i - 81920; which = 2; }
    int f = idx >> 9, lane = (idx >> 3) & 63, j = idx & 7;
    int kt = f >> 3, nt = f & 7;
    int k = kt * 32 + (lane >> 4) * 8 + j;
    int n = nt * 16 + (lane & 15);
    float v;
    if (which == 1 && kt >= 4) v = wfuse[(k - 128) * 128 + n];   // folded We2@Wn1b
    else                       v = W[k * H + n];
    wb[i] = (unsigned short)f2bfs(v);
}

// ---- counting sort of edges by destination (col) ----
__global__ void hist_col(const int* __restrict__ ei, int* __restrict__ cnt) {
    int e = blockIdx.x * 256 + threadIdx.x;
    if (e < N_EDGES) atomicAdd(&cnt[ei[N_EDGES + e]], 1);
}

__global__ void scan_hist(const int* __restrict__ cnt, int* __restrict__ cursor) {
    __shared__ int wsum[16];
    __shared__ int stot;
    __shared__ int sbase_s;
    const int tid = threadIdx.x;
    const int lane = tid & 63, wid = tid >> 6;
    if (tid == 0) sbase_s = 0;
    __syncthreads();
    for (int base = 0; base < N_NODES; base += 1024) {
        int i = base + tid;
        int v = (i < N_NODES) ? cnt[i] : 0;
        int incl = v;
#pragma unroll
        for (int off = 1; off < 64; off <<= 1) {
            int t = __shfl_up(incl, off);
            if (lane >= off) incl += t;
        }
        if (lane == 63) wsum[wid] = incl;
        __syncthreads();
        if (wid == 0) {
            int wv = (lane < 16) ? wsum[lane] : 0;
            int winc = wv;
#pragma unroll
            for (int off = 1; off < 16; off <<= 1) {
                int t = __shfl_up(winc, off);
                if (lane >= off) winc += t;
            }
            if (lane < 16) wsum[lane] = winc - wv;
            if (lane == 15) stot = winc;
        }
        __syncthreads();
        if (i < N_NODES) cursor[i] = sbase_s + wsum[wid] + (incl - v);
        __syncthreads();
        if (tid == 0) sbase_s += stot;
        __syncthreads();
    }
}

__global__ void build_perm(const int* __restrict__ ei, int* __restrict__ cursor,
                           int* __restrict__ perm) {
    int e = blockIdx.x * 256 + threadIdx.x;
    if (e < N_EDGES) {
        int pos = atomicAdd(&cursor[ei[N_EDGES + e]], 1);
        perm[pos] = e;
    }
}

// ---- XW = x @ [We1a | We1b]  -> fp32 [N][256].  1 wave = 16 rows, no LDS/barriers.
__launch_bounds__(256)
__global__ void xw_gemm(const float* __restrict__ x, const unsigned short* __restrict__ wb,
                        float* __restrict__ XW) {
    int tidx = blockIdx.x * 4 + (threadIdx.x >> 6);
    if (tidx >= 3125) return;                        // 3125*16 = 50000 exact
    const int lane = threadIdx.x & 63, c = lane & 15, quad = lane >> 4;
    const bf16x8* __restrict__ BW1 = (const bf16x8*)wb;
    const float* xr = x + (size_t)(tidx * 16 + c) * H;
    f32x4 acc[16];
#pragma unroll
    for (int j = 0; j < 16; ++j) acc[j] = (f32x4){0.f, 0.f, 0.f, 0.f};
#pragma unroll
    for (int kt = 0; kt < 4; ++kt) {
        bf16x8 a = cvt8(xr + kt * 32 + quad * 8);
#pragma unroll
        for (int j = 0; j < 16; ++j) {
            int frag = (j < 8) ? (kt * 8 + j) : ((kt + 4) * 8 + j - 8);
            bf16x8 b = BW1[frag * 64 + lane];
            acc[j] = __builtin_amdgcn_mfma_f32_16x16x32_bf16(a, b, acc[j], 0, 0, 0);
        }
    }
#pragma unroll
    for (int j = 0; j < 16; ++j)
#pragma unroll
        for (int r = 0; r < 4; ++r)
            XW[(size_t)(tidx * 16 + quad * 4 + r) * 256 + j * 16 + c] = acc[j][r];
}

// ---- EW chunk = ea[perm[p]] @ We1c + be1 -> bf16 [CHUNK][128] (sorted order).
__launch_bounds__(256)
__global__ void ea_gemm(const float* __restrict__ ea, const int* __restrict__ perm,
                        const float* __restrict__ be1, const unsigned short* __restrict__ wb,
                        unsigned short* __restrict__ EW, int p0c) {
    int w = blockIdx.x * 4 + (threadIdx.x >> 6);
    if (w >= CHUNK / 16) return;                     // 6250 waves
    const int lane = threadIdx.x & 63, c = lane & 15, quad = lane >> 4;
    const bf16x8* __restrict__ BW1 = (const bf16x8*)wb;
    int e = perm[p0c + w * 16 + c];
    const float* pea = ea + (size_t)e * H;
    float be1v[8];
#pragma unroll
    for (int nt = 0; nt < 8; ++nt) be1v[nt] = be1[nt * 16 + c];
    f32x4 acc[8];
#pragma unroll
    for (int nt = 0; nt < 8; ++nt)
        acc[nt] = (f32x4){be1v[nt], be1v[nt], be1v[nt], be1v[nt]};
#pragma unroll
    for (int kt = 0; kt < 4; ++kt) {
        bf16x8 a = cvt8(pea + kt * 32 + quad * 8);
#pragma unroll
        for (int nt = 0; nt < 8; ++nt) {
            bf16x8 b = BW1[((kt + 8) * 8 + nt) * 64 + lane];
            acc[nt] = __builtin_amdgcn_mfma_f32_16x16x32_bf16(a, b, acc[nt], 0, 0, 0);
        }
    }
#pragma unroll
    for (int nt = 0; nt < 8; ++nt)
#pragma unroll
        for (int r = 0; r < 4; ++r)
            EW[(size_t)(w * 16 + quad * 4 + r) * H + nt * 16 + c] = (unsigned short)f2bfs(acc[nt][r]);
}

// ---- hot kernel: S = EW + XWa[row] + XWb[col]; h = relu(S); segmented run-sum
//      over sorted dests -> coalesced fp32 atomic flush. No MFMA/LDS/barriers.
__launch_bounds__(256)
__global__ void edge_gather(const int* __restrict__ ei, const int* __restrict__ perm,
                            const unsigned short* __restrict__ EW, const float* __restrict__ XW,
                            float* __restrict__ aggH, int p0c) {
    int g = blockIdx.x * 4 + (threadIdx.x >> 6);
    if (g >= CHUNK / 16) return;                     // 6250 waves, 16 edges each
    const int lane = threadIdx.x & 63;
    int myp = perm[p0c + g * 16 + (lane & 15)];
    int myd = ei[N_EDGES + myp];
    int myr = ei[myp];
    const unsigned short* ewb = EW + (size_t)g * 16 * H;   // chunk-local rows
    float s0 = 0.f, s1 = 0.f;
    int dprev = __builtin_amdgcn_readlane(myd, 0);
#pragma unroll 4
    for (int i = 0; i < 16; ++i) {
        int di = __builtin_amdgcn_readlane(myd, i);
        int ri = __builtin_amdgcn_readlane(myr, i);
        const float* xa = XW + (size_t)ri * 256;
        const float* xb = XW + (size_t)di * 256 + 128;
        float v0 = bfs2f(ewb[i * H + lane])      + xa[lane]      + xb[lane];
        float v1 = bfs2f(ewb[i * H + 64 + lane]) + xa[64 + lane] + xb[64 + lane];
        v0 = v0 > 0.f ? v0 : 0.f;
        v1 = v1 > 0.f ? v1 : 0.f;
        if (i && di != dprev) {                      // wave-uniform branch
            atomicAdd(aggH + (size_t)dprev * H + lane, s0);
            atomicAdd(aggH + (size_t)dprev * H + 64 + lane, s1);
            s0 = v0; s1 = v1;
        } else {
            s0 += v0; s1 += v1;
        }
        dprev = di;
    }
    atomicAdd(aggH + (size_t)dprev * H + lane, s0);
    atomicAdd(aggH + (size_t)dprev * H + 64 + lane, s1);
}

// ---- node GEMM1: preact = x@Wn1a + bf16(aggH)@Wfuse + deg*c2 + bn1; relu;
//      h stored bf16 in GEMM-A fragment layout. No LDS/barriers.
__launch_bounds__(256)
__global__ void node1(const float* __restrict__ x, const float* __restrict__ aggH,
                      const int* __restrict__ cnt, const float* __restrict__ bn1,
                      const float* __restrict__ c2, const unsigned short* __restrict__ wb,
                      unsigned short* __restrict__ Hn) {
    int tidx = blockIdx.x * 4 + (threadIdx.x >> 6);
    if (tidx >= 3125) return;
    const int lane = threadIdx.x & 63, c = lane & 15, quad = lane >> 4;
    const bf16x8* __restrict__ BN1 = (const bf16x8*)(wb + 49152);
    const float* xr = x    + (size_t)(tidx * 16 + c) * H;
    const float* ar = aggH + (size_t)(tidx * 16 + c) * H;
    float b1v[8], c2v[8];
#pragma unroll
    for (int nt = 0; nt < 8; ++nt) {
        b1v[nt] = bn1[nt * 16 + c];
        c2v[nt] = c2[nt * 16 + c];
    }
    float dg[4];
#pragma unroll
    for (int r = 0; r < 4; ++r) dg[r] = (float)cnt[tidx * 16 + quad * 4 + r];
    f32x4 acc[8];
#pragma unroll
    for (int nt = 0; nt < 8; ++nt)
#pragma unroll
        for (int r = 0; r < 4; ++r)
            acc[nt][r] = b1v[nt] + dg[r] * c2v[nt];
#pragma unroll
    for (int kt = 0; kt < 8; ++kt) {
        const float* src = (kt < 4) ? (xr + kt * 32) : (ar + (kt - 4) * 32);
        bf16x8 a = cvt8(src + quad * 8);
#pragma unroll
        for (int nt = 0; nt < 8; ++nt) {
            bf16x8 b = BN1[(kt * 8 + nt) * 64 + lane];
            acc[nt] = __builtin_amdgcn_mfma_f32_16x16x32_bf16(a, b, acc[nt], 0, 0, 0);
        }
    }
    // relu + fragment-layout store: consumer frag elem (kt2,lane2,j) = h[row=lane2&15][col]
#pragma unroll
    for (int nt = 0; nt < 8; ++nt) {
        int kt2 = nt >> 1;
        int laneq = 16 * ((nt * 2 + (c >> 3)) & 3);
#pragma unroll
        for (int r = 0; r < 4; ++r) {
            float v = acc[nt][r];
            v = v > 0.f ? v : 0.f;
            Hn[(size_t)((tidx * 4 + kt2) * 64 + quad * 4 + r + laneq) * 8 + (c & 7)] =
                (unsigned short)f2bfs(v);
        }
    }
}

// ---- node GEMM2: out = h @ Wn2 + bn2.  A read directly in fragment layout.
__launch_bounds__(256)
__global__ void node2(const unsigned short* __restrict__ Hn, const float* __restrict__ bn2,
                      const unsigned short* __restrict__ wb, float* __restrict__ out) {
    int tidx = blockIdx.x * 4 + (threadIdx.x >> 6);
    if (tidx >= 3125) return;
    const int lane = threadIdx.x & 63, c = lane & 15, quad = lane >> 4;
    const bf16x8* __restrict__ BN2 = (const bf16x8*)(wb + 81920);
    float b2v[8];
#pragma unroll
    for (int nt = 0; nt < 8; ++nt) b2v[nt] = bn2[nt * 16 + c];
    f32x4 acc[8];
#pragma unroll
    for (int nt = 0; nt < 8; ++nt)
        acc[nt] = (f32x4){b2v[nt], b2v[nt], b2v[nt], b2v[nt]};
#pragma unroll
    for (int kt2 = 0; kt2 < 4; ++kt2) {
        bf16x8 a = *(const bf16x8*)&Hn[(size_t)((tidx * 4 + kt2) * 64 + lane) * 8];
#pragma unroll
        for (int nt = 0; nt < 8; ++nt) {
            bf16x8 b = BN2[(kt2 * 8 + nt) * 64 + lane];
            acc[nt] = __builtin_amdgcn_mfma_f32_16x16x32_bf16(a, b, acc[nt], 0, 0, 0);
        }
    }
#pragma unroll
    for (int nt = 0; nt < 8; ++nt)
#pragma unroll
        for (int r = 0; r < 4; ++r)
            out[(size_t)(tidx * 16 + quad * 4 + r) * H + nt * 16 + c] = acc[nt][r];
}

extern "C" void kernel_launch(void* const* d_in, const int* in_sizes, int n_in,
                              void* d_out, int out_size, void* d_ws, size_t ws_size,
                              hipStream_t stream) {
    const float* x   = (const float*)d_in[0];
    const int*   ei  = (const int*)d_in[1];
    const float* ea  = (const float*)d_in[2];
    const float* We1 = (const float*)d_in[3];
    const float* be1 = (const float*)d_in[4];
    const float* We2 = (const float*)d_in[5];
    const float* be2 = (const float*)d_in[6];
    const float* Wn1 = (const float*)d_in[7];
    const float* bn1 = (const float*)d_in[8];
    const float* Wn2 = (const float*)d_in[9];
    const float* bn2 = (const float*)d_in[10];
    float* out = (float*)d_out;

    // workspace layout (101.4 MB):
    //   wb     @ 0          (256 KB, bf16 weight frags)
    //   wfuse  @ 262144     (64 KB fp32)
    //   c2     @ 327680     (4 KB fp32)
    //   aggH   @ 331776     (25.6 MB fp32)
    //   cnt    @ 25931776   (200 KB int, = in-degree, reused by node1)
    //   cur    @ 26131776   (200 KB int)
    //   perm   @ 26331776   (3.2 MB int)
    //   XW     @ 29531776   (51.2 MB fp32 [N][256])
    //   EW/Hn  @ 80731776   (25.6 MB: bf16 EW chunk; reused as 12.8 MB Hn)
    char* base = (char*)d_ws;
    unsigned short* wb    = (unsigned short*)base;
    float*          wfuse = (float*)(base + 262144);
    float*          c2    = (float*)(base + 327680);
    float*          aggH  = (float*)(base + 331776);
    int*            cnt   = (int*)(base + 25931776);
    int*            cur   = (int*)(base + 26131776);
    int*            perm  = (int*)(base + 26331776);
    float*          XW    = (float*)(base + 29531776);
    unsigned short* EW    = (unsigned short*)(base + 80731776);
    unsigned short* Hn    = EW;   // reused after last edge_gather

    hipMemsetAsync(aggH, 0, 25600000 + 200000, stream);   // aggH + cnt contiguous
    wfuse_c2<<<129, 128, 0, stream>>>(We2, Wn1, be2, wfuse, c2);
    prep_weights<<<384, 256, 0, stream>>>(We1, Wn1, Wn2, wfuse, wb);
    xw_gemm<<<782, 256, 0, stream>>>(x, wb, XW);
    hist_col<<<3125, 256, 0, stream>>>(ei, cnt);
    scan_hist<<<1, 1024, 0, stream>>>(cnt, cur);
    build_perm<<<3125, 256, 0, stream>>>(ei, cur, perm);
    for (int cch = 0; cch < 8; ++cch) {
        ea_gemm<<<1563, 256, 0, stream>>>(ea, perm, be1, wb, EW, cch * CHUNK);
        edge_gather<<<1563, 256, 0, stream>>>(ei, perm, EW, XW, aggH, cch * CHUNK);
    }
    node1<<<782, 256, 0, stream>>>(x, aggH, cnt, bn1, c2, wb, Hn);
    node2<<<782, 256, 0, stream>>>(Hn, bn2, wb, out);
}